// Round 3
// baseline (404.136 us; speedup 1.0000x reference)
//
#include <hip/hip_runtime.h>

#define IMG    224
#define NPIX   (IMG * IMG)       // 50176
#define NELEM  (NPIX * 3)        // 150528
#define KSEL   12544             // 0.25 * IMG * IMG
#define NBINS  4096
#define MAXCAND 1024
#define BLOCK  1024
#define NWAVE  (BLOCK / 64)      // 16
#define SPLIT  2                 // blocks per sample for heavy kernels
#define NPIX4  (NPIX / 4)        // 12544 pixel-float4 groups per sample
#define GVEC   (NELEM / 4)       // 37632 grad float4 per sample
#define HGVEC  (GVEC / SPLIT)    // 18816 grad float4 per K1 block
#define PGRP   (NPIX4 / SPLIT)   // 6272 pixel groups per K3 block

typedef float f4 __attribute__((ext_vector_type(4)));

__device__ __forceinline__ int binof(float x) {
    return min((int)(x * 4096.0f), NBINS - 1);
}

// ---------------- K1: partial histogram, 2 blocks/sample ----------------
__global__ __launch_bounds__(BLOCK) void k1_hist(
    const float* __restrict__ grad, unsigned int* __restrict__ hist)
{
    const int smp  = blockIdx.x / SPLIT;
    const int half = blockIdx.x % SPLIT;
    const int tid  = threadIdx.x;

    __shared__ unsigned int lh[NBINS];
    for (int i = tid; i < NBINS; i += BLOCK) lh[i] = 0u;
    __syncthreads();

    const f4* g4 = (const f4*)(grad + (size_t)smp * NELEM) + (size_t)half * HGVEC;

    int i = tid;
    for (; i + 3 * BLOCK < HGVEC; i += 4 * BLOCK) {
        f4 v0 = g4[i];
        f4 v1 = g4[i + BLOCK];
        f4 v2 = g4[i + 2 * BLOCK];
        f4 v3 = g4[i + 3 * BLOCK];
        #pragma unroll
        for (int c = 0; c < 4; ++c) atomicAdd(&lh[binof(v0[c])], 1u);
        #pragma unroll
        for (int c = 0; c < 4; ++c) atomicAdd(&lh[binof(v1[c])], 1u);
        #pragma unroll
        for (int c = 0; c < 4; ++c) atomicAdd(&lh[binof(v2[c])], 1u);
        #pragma unroll
        for (int c = 0; c < 4; ++c) atomicAdd(&lh[binof(v3[c])], 1u);
    }
    for (; i < HGVEC; i += BLOCK) {
        f4 v = g4[i];
        #pragma unroll
        for (int c = 0; c < 4; ++c) atomicAdd(&lh[binof(v[c])], 1u);
    }
    __syncthreads();

    unsigned int* h = hist + (size_t)smp * NBINS;
    for (int i2 = tid; i2 < NBINS; i2 += BLOCK) atomicAdd(&h[i2], lh[i2]);
}

// ---------------- K2: per-sample threshold (suffix scan) ----------------
__global__ __launch_bounds__(BLOCK) void k2_thresh(
    const unsigned int* __restrict__ hist,
    int* __restrict__ B1a, unsigned int* __restrict__ Ra)
{
    const int smp  = blockIdx.x;
    const int tid  = threadIdx.x;
    const int lane = tid & 63;
    const int wid  = tid >> 6;

    __shared__ unsigned int wtot[NWAVE];

    uint4 h = ((const uint4*)(hist + (size_t)smp * NBINS))[tid];
    unsigned int s = h.x + h.y + h.z + h.w;

    unsigned int v = s;
    #pragma unroll
    for (int off = 1; off < 64; off <<= 1) {
        unsigned int u = __shfl_down(v, off);
        if (lane + off < 64) v += u;
    }
    if (lane == 0) wtot[wid] = v;
    __syncthreads();

    unsigned int woff = 0;
    for (int w = wid + 1; w < NWAVE; ++w) woff += wtot[w];

    unsigned int a  = v + woff;   // suffix sum starting at group tid
    unsigned int nx = a - s;      // suffix sum starting at group tid+1

    if (a >= KSEL && nx < KSEL) {
        unsigned int hh[4] = {h.x, h.y, h.z, h.w};
        unsigned int cum = nx;
        for (int i = 3; i >= 0; --i) {
            cum += hh[i];
            if (cum >= KSEL) {
                B1a[smp] = 4 * tid + i;
                Ra[smp]  = KSEL - (cum - hh[i]);
                break;
            }
        }
    }
}

// ---- K3: fused classify + masked output, 2 blocks/sample, pixel-aligned ----
__global__ __launch_bounds__(BLOCK) void k3_out(
    const float* __restrict__ data, const float* __restrict__ grad,
    float* __restrict__ out,
    const int* __restrict__ B1a,
    unsigned int* __restrict__ candcnt,
    unsigned int* __restrict__ candkey, unsigned int* __restrict__ candidx)
{
    const int smp  = blockIdx.x / SPLIT;
    const int half = blockIdx.x % SPLIT;
    const int tid  = threadIdx.x;
    const int B1   = B1a[smp];

    const f4* g4 = (const f4*)(grad + (size_t)smp * NELEM);
    const f4* d4 = (const f4*)(data + (size_t)smp * NELEM);
    f4*       o4 = (f4*)(out + (size_t)smp * NELEM);

    unsigned int* ck = candkey + (size_t)smp * MAXCAND;
    unsigned int* ci = candidx + (size_t)smp * MAXCAND;

    auto push = [&](float val, unsigned int idx) {
        unsigned int c2 = atomicAdd(&candcnt[smp], 1u);
        if (c2 < MAXCAND) {
            ck[c2] = __float_as_uint(val);   // nonneg: uint order == float order
            ci[c2] = idx;
        }
    };

    for (int q = tid; q < PGRP; q += BLOCK) {
        const int G = half * PGRP + q;       // pixel-float4 group in sample
        // grad: 3 coalesced plane reads (element e -> pixel e mod NPIX)
        f4 pa = g4[G];
        f4 pb = g4[G + NPIX4];
        f4 pc = g4[G + 2 * NPIX4];
        // data for pixels 4G..4G+3 = elements 12G..12G+11
        f4 x0 = __builtin_nontemporal_load(&d4[3 * G]);
        f4 x1 = __builtin_nontemporal_load(&d4[3 * G + 1]);
        f4 x2 = __builtin_nontemporal_load(&d4[3 * G + 2]);

        bool m[4];
        #pragma unroll
        for (int j = 0; j < 4; ++j) {
            int ba = binof(pa[j]);
            int bb = binof(pb[j]);
            int bc = binof(pc[j]);
            m[j] = (ba > B1) || (bb > B1) || (bc > B1);
            unsigned int p = (unsigned int)(4 * G + j);
            if (ba == B1) push(pa[j], p);
            if (bb == B1) push(pb[j], p + NPIX);
            if (bc == B1) push(pc[j], p + 2 * NPIX);
        }

        // x0 = {(p0,c0),(p0,c1),(p0,c2),(p1,c0)}
        if (m[0]) { x0.x = 0.0f; x0.y = 0.0f; x0.z = 0.0f; }
        if (m[1]) { x0.w = 0.0f; x1.x = 0.0f; x1.y = 0.0f; }
        if (m[2]) { x1.z = 0.0f; x1.w = 0.0f; x2.x = 0.0f; }
        if (m[3]) { x2.y = 0.0f; x2.z = 0.0f; x2.w = 0.0f; }

        __builtin_nontemporal_store(x0, &o4[3 * G]);
        __builtin_nontemporal_store(x1, &o4[3 * G + 1]);
        __builtin_nontemporal_store(x2, &o4[3 * G + 2]);
    }
}

// -------- K4: exact rank among bin==B1 candidates, zero selected pixels ------
__global__ __launch_bounds__(256) void k4_fix(
    float* __restrict__ out,
    const unsigned int* __restrict__ candcnt,
    const unsigned int* __restrict__ candkey,
    const unsigned int* __restrict__ candidx,
    const unsigned int* __restrict__ Ra)
{
    const int smp = blockIdx.x;
    const int t   = threadIdx.x;

    __shared__ unsigned int sk[MAXCAND];
    __shared__ unsigned int si[MAXCAND];

    unsigned int n = candcnt[smp];
    if (n > MAXCAND) n = MAXCAND;
    unsigned int r = Ra[smp];

    const unsigned int* ck = candkey + (size_t)smp * MAXCAND;
    const unsigned int* ci = candidx + (size_t)smp * MAXCAND;
    for (unsigned int j = t; j < n; j += 256) { sk[j] = ck[j]; si[j] = ci[j]; }
    __syncthreads();

    for (unsigned int j = t; j < n; j += 256) {
        unsigned int kj = sk[j];
        unsigned int ij = si[j];
        unsigned int rank = 0;
        for (unsigned int i = 0; i < n; ++i) {
            unsigned int ki = sk[i];
            rank += (ki > kj) || (ki == kj && si[i] < ij);
        }
        if (rank < r) {
            unsigned int p = ij % NPIX;
            float* op = out + (size_t)smp * NELEM + 3u * p;
            op[0] = 0.0f; op[1] = 0.0f; op[2] = 0.0f;
        }
    }
}

// ===================== fallback: verified single-kernel path =====================
__global__ __launch_bounds__(BLOCK) void masked_model_kernel(
    const float* __restrict__ data,
    const float* __restrict__ grad,
    float* __restrict__ out)
{
    const int b    = blockIdx.x;
    const int tid  = threadIdx.x;
    const int lane = tid & 63;
    const int wid  = tid >> 6;

    const float* g = grad + (size_t)b * NELEM;
    const float* d = data + (size_t)b * NELEM;
    float*       o = out  + (size_t)b * NELEM;

    __shared__ unsigned int hist[NBINS];
    __shared__ unsigned int mask[NPIX / 32];
    __shared__ unsigned int candkey[MAXCAND];
    __shared__ unsigned int candidx[MAXCAND];
    __shared__ unsigned int wtot[NWAVE];
    __shared__ unsigned int candcnt;
    __shared__ int sB1;
    __shared__ unsigned int sR;

    for (int i = tid; i < NBINS; i += BLOCK) hist[i] = 0u;
    for (int i = tid; i < NPIX / 32; i += BLOCK) mask[i] = 0u;
    if (tid == 0) candcnt = 0u;
    __syncthreads();

    const f4* g4 = (const f4*)g;
    for (int i = tid; i < GVEC; i += BLOCK) {
        f4 v = g4[i];
        #pragma unroll
        for (int c = 0; c < 4; ++c) atomicAdd(&hist[binof(v[c])], 1u);
    }
    __syncthreads();

    {
        unsigned int s = hist[4 * tid] + hist[4 * tid + 1]
                       + hist[4 * tid + 2] + hist[4 * tid + 3];
        unsigned int v = s;
        #pragma unroll
        for (int off = 1; off < 64; off <<= 1) {
            unsigned int u = __shfl_down(v, off);
            if (lane + off < 64) v += u;
        }
        if (lane == 0) wtot[wid] = v;
        __syncthreads();
        unsigned int woff = 0;
        for (int w = wid + 1; w < NWAVE; ++w) woff += wtot[w];
        unsigned int a  = v + woff;
        unsigned int nx = a - s;
        if (a >= KSEL && nx < KSEL) {
            unsigned int cum = nx;
            for (int i = 3; i >= 0; --i) {
                unsigned int h = hist[4 * tid + i];
                cum += h;
                if (cum >= KSEL) { sB1 = 4 * tid + i; sR = KSEL - (cum - h); break; }
            }
        }
    }
    __syncthreads();

    {
        const int B1 = sB1;
        for (int i = tid; i < GVEC; i += BLOCK) {
            f4 v = g4[i];
            #pragma unroll
            for (int c = 0; c < 4; ++c) {
                int bin = binof(v[c]);
                int idx = 4 * i + c;
                if (bin > B1) {
                    int p = idx % NPIX;
                    atomicOr(&mask[p >> 5], 1u << (p & 31));
                } else if (bin == B1) {
                    unsigned int c2 = atomicAdd(&candcnt, 1u);
                    if (c2 < MAXCAND) {
                        candkey[c2] = __float_as_uint(v[c]);
                        candidx[c2] = (unsigned int)idx;
                    }
                }
            }
        }
    }
    __syncthreads();

    {
        unsigned int n = candcnt < MAXCAND ? candcnt : MAXCAND;
        unsigned int r = sR;
        for (unsigned int j = tid; j < n; j += BLOCK) {
            unsigned int kj = candkey[j];
            unsigned int ij = candidx[j];
            unsigned int rank = 0;
            for (unsigned int i = 0; i < n; ++i) {
                unsigned int ki = candkey[i];
                rank += (ki > kj) || (ki == kj && candidx[i] < ij);
            }
            if (rank < r) {
                int p = (int)(ij % NPIX);
                atomicOr(&mask[p >> 5], 1u << (p & 31));
            }
        }
    }
    __syncthreads();

    {
        const f4* d4 = (const f4*)d;
        f4*       o4 = (f4*)o;
        for (int i = tid; i < GVEC; i += BLOCK) {
            f4 v = d4[i];
            int e = 4 * i;
            int p0 = e / 3, p1 = (e + 1) / 3, p2 = (e + 2) / 3, p3 = (e + 3) / 3;
            if ((mask[p0 >> 5] >> (p0 & 31)) & 1u) v.x = 0.0f;
            if ((mask[p1 >> 5] >> (p1 & 31)) & 1u) v.y = 0.0f;
            if ((mask[p2 >> 5] >> (p2 & 31)) & 1u) v.z = 0.0f;
            if ((mask[p3 >> 5] >> (p3 & 31)) & 1u) v.w = 0.0f;
            o4[i] = v;
        }
    }
}

extern "C" void kernel_launch(void* const* d_in, const int* in_sizes, int n_in,
                              void* d_out, int out_size, void* d_ws, size_t ws_size,
                              hipStream_t stream) {
    const float* data = (const float*)d_in[0];   // [256, 224, 224, 3] fp32
    const float* grad = (const float*)d_in[1];   // [256, 150528] fp32
    float* out = (float*)d_out;                  // [256, 224, 224, 3] fp32

    const int B = in_sizes[0] / NELEM;           // 256

    // workspace layout (all u32): hist[B][4096] | candcnt[B] | B1[B] | R[B]
    //                           | candkey[B][MAXCAND] | candidx[B][MAXCAND]
    const size_t histB  = (size_t)B * NBINS * 4;
    const size_t cntB   = (size_t)B * 4;
    const size_t candB  = (size_t)B * MAXCAND * 4;
    const size_t needed = histB + 3 * cntB + 2 * candB;

    if (ws_size < needed) {
        // fallback: verified single-kernel path
        masked_model_kernel<<<B, BLOCK, 0, stream>>>(data, grad, out);
        return;
    }

    char* ws = (char*)d_ws;
    unsigned int* hist    = (unsigned int*)(ws);
    unsigned int* candcnt = (unsigned int*)(ws + histB);
    int*          B1a     = (int*)         (ws + histB + cntB);
    unsigned int* Ra      = (unsigned int*)(ws + histB + 2 * cntB);
    unsigned int* candkey = (unsigned int*)(ws + histB + 3 * cntB);
    unsigned int* candidx = (unsigned int*)(ws + histB + 3 * cntB + candB);

    // zero hist + candcnt (contiguous)
    hipMemsetAsync(ws, 0, histB + cntB, stream);

    k1_hist  <<<B * SPLIT, BLOCK, 0, stream>>>(grad, hist);
    k2_thresh<<<B,         BLOCK, 0, stream>>>(hist, B1a, Ra);
    k3_out   <<<B * SPLIT, BLOCK, 0, stream>>>(data, grad, out, B1a, candcnt, candkey, candidx);
    k4_fix   <<<B,         256,   0, stream>>>(out, candcnt, candkey, candidx, Ra);
}